// Round 1
// baseline (144.172 us; speedup 1.0000x reference)
//
#include <hip/hip_runtime.h>

// LatticeFilter: step-up (Levinson-Durbin) recursion, rc -> LPC coeffs.
//   rc: (B=16, p=128, Tf=8192) fp32, k_i = 0.98*rc[b,i,t]
//   out: (B, Tf, p+1=129) fp32, a[...,0]=1
//
// R6 theory: two pathologies in the R5 kernel.
//  (1) VGPR_Count=112 (+16 AGPR = exactly the 4-wave/EU 128-reg budget):
//      amdgpu_waves_per_eu(2,2) was NOT honored; hot a[] tail shuttled
//      through AGPRs -> VALUBusy 27.9us vs 13.8us FMA floor.
//  (2) grid == resident capacity (512 blk x 4 waves @ 2 waves/SIMD):
//      all waves phase-locked -> 64.5 MiB store phase fully serialized
//      after compute (~25us of VALU-idle time).
// Fixes:
//  (a) 64-thread (1-wave) blocks, waves_per_eu(1,1) -> 512-reg budget.
//      Prefetch ALL 128 k's upfront: kq[] dies exactly as a[] grows, so
//      live pressure is flat ~135 regs; if the budget is still capped,
//      the coldest values (kq slots, 1 write + 1 read each) spill first,
//      not the hot a[] -> graceful degradation. No ring, no clobbers;
//      per-value waitcnts let the recursion consume loads progressively.
//  (b) 33 KB LDS/block caps residency at 4 blocks/CU = 1 wave/SIMD by
//      construction -> 2048 blocks / 1024 resident = 2 generations:
//      gen-2 compute overlaps gen-1 store drain. Single-wave issue is
//      fine: step M has (M-1)-wide ILP vs 4-cyc dep / 2-cyc issue.
//  (c) epilogue: 1 round / 1 barrier (was 4 rounds / 8 barriers); same
//      conflict-free stride-129 staging + coalesced float4 stores.

#define NB   16
#define ORD  128
#define TF   8192

// ---- pair update j <-> m-j, both reading pre-step values (tmp-swap) ----
template<int M, int J>
struct PairUpd {
    static __device__ __forceinline__ void run(float (&a)[ORD + 1], float k) {
        const float lo = a[J];
        const float hi = a[M - J];
        a[J]     = fmaf(k, hi, lo);
        a[M - J] = fmaf(k, lo, hi);
        if constexpr (2 * (J + 1) < M) PairUpd<M, J + 1>::run(a, k);
    }
};

template<int M>
struct Step {
    static __device__ __forceinline__ void run(float (&a)[ORD + 1],
                                               const float (&kq)[ORD]) {
        const float k = 0.98f * kq[M - 1];
        if constexpr (M > 2) PairUpd<M, 1>::run(a, k);
        if constexpr ((M & 1) == 0) {           // middle element self-update
            const float mid = a[M / 2];
            a[M / 2] = fmaf(k, mid, mid);
        }
        a[M] = k;                               // a[0] == 1 contributes k
        if constexpr (M < ORD) Step<M + 1>::run(a, kq);
    }
};

// ---- LDS staging, static indices (compiler merges into ds_write_b128) ----
template<int J>
struct Stage {
    static __device__ __forceinline__ void run(float* __restrict__ dst,
                                               const float (&a)[ORD + 1]) {
        dst[J] = a[J];
        if constexpr (J < ORD) Stage<J + 1>::run(dst, a);
    }
};

__global__ __launch_bounds__(64)
__attribute__((amdgpu_waves_per_eu(1, 1)))
void lpc_stepup_kernel(const float* __restrict__ rc, float* __restrict__ out) {
    const int lane = threadIdx.x;                 // 0..63, one wave per block
    const int gid  = blockIdx.x * 64 + lane;      // flattened (B*Tf) column
    const int b = gid >> 13;                      // gid / TF (uniform per block)
    const int t = gid & (TF - 1);                 // gid % TF
    const float* rcp = rc + ((size_t)b * ORD) * TF + t;

    // ---- prefetch the whole k column: 128 coalesced dword loads ----
    // pressure stays flat: kq[i] dies at step i+1 exactly as a[i+1] is born
    float kq[ORD];
#pragma unroll
    for (int i = 0; i < ORD; ++i) kq[i] = rcp[(size_t)i * TF];

    float a[ORD + 1];
    a[0] = 1.0f;
    Step<1>::run(a, kq);                          // straight-line, reg-resident

    // ---- epilogue: transpose 64 rows x 129 cols through LDS, 1 round ----
    // stage: bank stride 1 (129 mod 32 = 1) -> free 2-way wave64 aliasing
    // store: 2064 contiguous float4 -> every 128B line written whole
    // 33,024 B LDS -> 4 blocks/CU -> 1 wave/SIMD residency BY CONSTRUCTION
    __shared__ __align__(16) float lds[64 * (ORD + 1)];
    Stage<0>::run(&lds[lane * (ORD + 1)], a);
    __syncthreads();                              // 1-wave barrier: ~free

    const float4* lds4 = (const float4*)lds;
    float4* out4 = (float4*)(out + (size_t)blockIdx.x * 64 * (ORD + 1));
#pragma unroll 4
    for (int e = lane; e < (64 * (ORD + 1)) / 4; e += 64)
        out4[e] = lds4[e];                        // perfectly coalesced
}

extern "C" void kernel_launch(void* const* d_in, const int* in_sizes, int n_in,
                              void* d_out, int out_size, void* d_ws, size_t ws_size,
                              hipStream_t stream) {
    // d_in[0] = excitation (dead in reference), d_in[1] = rc
    const float* rc = (const float*)d_in[1];
    float* out = (float*)d_out;
    dim3 grid((NB * TF) / 64);   // 2048 one-wave blocks: 2 generations/SIMD
    dim3 block(64);
    hipLaunchKernelGGL(lpc_stepup_kernel, grid, block, 0, stream, rc, out);
}